// Round 6
// baseline (761.673 us; speedup 1.0000x reference)
//
#include <hip/hip_runtime.h>
#include <cstdint>
#include <cstddef>

// Sizes: B=16, T=8, K=4, DIN=9408, H1=1024, F=512, MH=128
#define NB 512

// ---------------- init: zero grid-barrier counters (every replay) ----------------
// 8 slots x 1024 ints (32 counters spaced 32 ints = 128 B apart) = 8192 ints.
__global__ void init_kernel(int* bar) {
  bar[blockIdx.x * 256 + threadIdx.x] = 0;
}

// ---------------- spread-counter grid barrier ----------------
// Arrival: relaxed atomicAdd to 1 of 32 line-spaced counters (<=16 serialized
// RMWs per line instead of 512 at one address -- round-5's 42us/barrier bug).
// Poll: wave 0, lanes 0-31 load the 32 counters in ONE wave instruction
// (relaxed, no per-poll cache maintenance), shfl-reduce, sleep-retry.
// Fences identical to round 5 (correctness-proven): one release threadfence
// before arrival, one acquire threadfence after the count is reached.
__device__ __forceinline__ void gbar(int* bar, int slot, int n) {
  __syncthreads();
  int* ctr = bar + (slot << 10);
  if (threadIdx.x == 0) {
    __threadfence();                                  // release: L2 writeback
    __hip_atomic_fetch_add(ctr + ((blockIdx.x & 31) << 5), 1,
                           __ATOMIC_RELAXED, __HIP_MEMORY_SCOPE_AGENT);
  }
  if (threadIdx.x < 64) {
    while (true) {
      int v = 0;
      if (threadIdx.x < 32)
        v = __hip_atomic_load(ctr + (threadIdx.x << 5),
                              __ATOMIC_RELAXED, __HIP_MEMORY_SCOPE_AGENT);
#pragma unroll
      for (int o = 32; o; o >>= 1) v += __shfl_xor(v, o);
      if (v >= n) break;
      __builtin_amdgcn_s_sleep(8);
    }
    if (threadIdx.x == 0) __threadfence();            // acquire (once)
  }
  __syncthreads();
}

// ---------------- skinny GEMM phase body (M=16, VEC=2, software-pipelined) ----
// Stages (optionally scaled) A-chunk to LDS [kk*20+b] once, then NPASS sweeps
// of 512 columns each (j0 = pass*512 + tid*2), writing P[c][16][N].
template<int KC, int UF, int NPASS>
__device__ __forceinline__ void gemm_body(
    float* sh, const float* __restrict__ A, int lda, int iLoc0,
    const float* scales, int sstride,          // scale per b; nullptr => 1
    const float* __restrict__ B,               // chunk base (row 0)
    int N, float* __restrict__ P, int c)
{
  static_assert(KC % UF == 0, "");
  constexpr int NG = KC / UF;
  static_assert(NG >= 2, "");
  const int tid = threadIdx.x;

  for (int b = 0; b < 16; ++b) {
    float s = scales ? scales[b * sstride] : 1.f;
    const float* Arow = A + (size_t)b * lda + iLoc0;
    for (int kk = tid; kk < KC; kk += 256)
      sh[kk * 20 + b] = s * Arow[kk];
  }
  __syncthreads();

#pragma unroll 1
  for (int pass = 0; pass < NPASS; ++pass) {
    const int j0 = pass * 512 + tid * 2;
    const float* Brow = B + j0;

    float acc[16][2];
#pragma unroll
    for (int b = 0; b < 16; ++b) { acc[b][0] = 0.f; acc[b][1] = 0.f; }

    float w0[UF][2], w1[UF][2];
    auto loadg = [&](float (&W)[UF][2], int kb) {
#pragma unroll
      for (int u = 0; u < UF; ++u) {
        float2 t2 = *reinterpret_cast<const float2*>(Brow + (size_t)(kb + u) * N);
        W[u][0] = t2.x; W[u][1] = t2.y;
      }
    };
    auto comp = [&](const float (&W)[UF][2], int kb) {
#pragma unroll
      for (int u = 0; u < UF; ++u) {
        int kk = kb + u;
        const float4 a0 = *reinterpret_cast<const float4*>(&sh[kk * 20 + 0]);
        const float4 a1 = *reinterpret_cast<const float4*>(&sh[kk * 20 + 4]);
        const float4 a2 = *reinterpret_cast<const float4*>(&sh[kk * 20 + 8]);
        const float4 a3 = *reinterpret_cast<const float4*>(&sh[kk * 20 + 12]);
        const float av[16] = {a0.x, a0.y, a0.z, a0.w, a1.x, a1.y, a1.z, a1.w,
                              a2.x, a2.y, a2.z, a2.w, a3.x, a3.y, a3.z, a3.w};
#pragma unroll
        for (int b = 0; b < 16; ++b) {
          acc[b][0] = fmaf(av[b], W[u][0], acc[b][0]);
          acc[b][1] = fmaf(av[b], W[u][1], acc[b][1]);
        }
      }
    };

    loadg(w0, 0);
    if constexpr (NG % 2 == 0) {
#pragma unroll 1
      for (int g = 0; g + 2 < NG; g += 2) {
        loadg(w1, (g + 1) * UF);
        comp(w0, g * UF);
        loadg(w0, (g + 2) * UF);
        comp(w1, (g + 1) * UF);
      }
      loadg(w1, (NG - 1) * UF);
      comp(w0, (NG - 2) * UF);
      comp(w1, (NG - 1) * UF);
    } else {
#pragma unroll 1
      for (int g = 0; g + 3 < NG; g += 2) {
        loadg(w1, (g + 1) * UF);
        comp(w0, g * UF);
        loadg(w0, (g + 2) * UF);
        comp(w1, (g + 1) * UF);
      }
      loadg(w1, (NG - 2) * UF);
      comp(w0, (NG - 3) * UF);
      loadg(w0, (NG - 1) * UF);
      comp(w1, (NG - 2) * UF);
      comp(w0, (NG - 1) * UF);
    }

    float* Pb = P + ((size_t)c * 16) * N + j0;
#pragma unroll
    for (int b = 0; b < 16; ++b) {
      *reinterpret_cast<float2*>(Pb) = make_float2(acc[b][0], acc[b][1]);
      Pb += N;
    }
  }
}

// ---------------- reduce phase body ----------------
// SL slices x CPS chunks; (256/SL) f-cols per block.
// MODE 1: z1,t1=(+b1,relu)  2: base=(+b2)  3: h (per-slice cW1 scale, t==s)  4: out
template<int CPS, int FTOT, int MODE, int SL>
__device__ __forceinline__ void reduce_phase(
    float* sh, const float* __restrict__ P,
    const float* __restrict__ bias, const float* __restrict__ coefs,
    const float* __restrict__ dvec,
    float* __restrict__ o1, float* __restrict__ o2, int blk)
{
  constexpr int COLS = 256 / SL;
  if (blk >= FTOT / COLS) return;
  float (*r)[COLS + 1] = (float(*)[COLS + 1])sh;
  const int fl = threadIdx.x % COLS, s = threadIdx.x / COLS;
  const int f = blk * COLS + fl;

  const float* p = P + (size_t)s * CPS * FTOT + f;
  float sum = 0.f;
#pragma unroll 4
  for (int cc = 0; cc < CPS; ++cc) { sum += *p; p += FTOT; }
  if constexpr (MODE == 3) {
    int b = f >> 10;
    sum *= coefs[b * 32 + s * 4 + 0];   // cW1[b, t=s]  (SL==8)
  }
  r[s][fl] = sum;
  __syncthreads();

  if (s == 0) {
    float v = 0.f;
#pragma unroll
    for (int i = 0; i < SL; ++i) v += r[i][fl];
    if constexpr (MODE == 1) {
      float z = v + bias[f & 1023];
      o1[f] = z;
      o2[f] = fmaxf(z, 0.f);
    } else if constexpr (MODE == 2) {
      o1[f] = v + bias[f & 511];
    } else if constexpr (MODE == 3) {
      int b = f >> 10, j = f & 1023;
      float z = v + bias[f];            // bias = z1
#pragma unroll
      for (int t = 0; t < 8; ++t) z = fmaf(coefs[b * 32 + t * 4 + 1], dvec[t * 1024 + j], z);
      o1[f] = fmaxf(z, 0.f);
    } else {
      int b = f >> 9, k = f & 511;
      float z = v + bias[k];            // bias = b2
#pragma unroll
      for (int t = 0; t < 8; ++t) z = fmaf(coefs[b * 32 + t * 4 + 3], dvec[t * 512 + k], z);
      o1[f] = z;
    }
  }
  __syncthreads();
}

// ---------------- the mega-kernel ----------------
// Blocks [0,256): small chain G1->R1->G2->R2->mcoef (sub-barriers, count 256).
// Blocks [256,512): G3 (dW1, 308 MB) concurrently. Join, then R3->G4->R4.
__global__ __launch_bounds__(256, 2) void mega_kernel(
    const float* __restrict__ x,
    const float* __restrict__ W1, const float* __restrict__ b1,
    const float* __restrict__ W2, const float* __restrict__ b2,
    const float* __restrict__ dW1, const float* __restrict__ db1,
    const float* __restrict__ dW2, const float* __restrict__ db2,
    const float* __restrict__ mW1, const float* __restrict__ mb1,
    const float* __restrict__ mW2, const float* __restrict__ mb2,
    float* __restrict__ out, float* __restrict__ ws, int* __restrict__ bar)
{
  const int blk = blockIdx.x, tid = threadIdx.x;
  __shared__ float sh[294 * 20];   // 23.5 KB, unioned across phases

  float* xp    = ws + 8192;          // after bar region (8192 ints)
  float* z1    = xp + 150528;
  float* t1    = z1 + 16384;
  float* base  = t1 + 16384;
  float* coefs = base + 8192;
  float* h     = coefs + 512;
  float* P1    = h + 16384;          // 224*16384 = 3670016
  float* P2    = P1 + 3670016;       // 32*8192   = 262144
  float* P3    = P2 + 262144;        // 256*16384 = 4194304
  float* P4    = P3 + 4194304;       // 288*8192  = 2359296

  // ---- P0: pool (all blocks) ----
  for (int tile = blk; tile < 588; tile += NB) {
    int idx = tile * 256 + tid;
    int bc = idx / 3136;
    int rr = idx - bc * 3136;
    int i  = rr / 56;
    int j  = rr - i * 56;
    const float* src = x + ((size_t)bc * 224 + 4 * i) * 224 + 4 * j;
    float s = 0.f;
#pragma unroll
    for (int q = 0; q < 4; ++q) {
      float4 v = *reinterpret_cast<const float4*>(src + q * 224);
      s += v.x + v.y + v.z + v.w;
    }
    xp[idx] = s * 0.0625f;
  }
  gbar(bar, 0, NB);

  if (blk < 256) {
    // ---- SMALL chain (sub-barriers among 256 blocks) ----
    // G1 = xp @ W1 -> P1  (224 chunks KC=42, 2 passes of 512 cols)
    if (blk < 224)
      gemm_body<42, 7, 2>(sh, xp, 9408, blk * 42, nullptr, 0,
                          W1 + (size_t)(blk * 42) * 1024, 1024, P1, blk);
    gbar(bar, 1, 256);

    // R1 -> z1, t1   (256 blocks, 64 cols x 4 slices, CPS=56)
    reduce_phase<56, 16384, 1, 4>(sh, P1, b1, nullptr, nullptr, z1, t1, blk);
    gbar(bar, 2, 256);

    // G2 = t1 @ W2 -> P2  (32 chunks KC=32)
    if (blk < 32)
      gemm_body<32, 8, 1>(sh, t1, 1024, blk * 32, nullptr, 0,
                          W2 + (size_t)(blk * 32) * 512, 512, P2, blk);
    gbar(bar, 3, 256);

    // R2 -> base  (128 blocks, 64 cols x 4 slices, CPS=8)
    reduce_phase<8, 8192, 2, 4>(sh, P2, b2, nullptr, nullptr, base, nullptr, blk);
    gbar(bar, 4, 256);

    // mcoef -> coefs (16 blocks)
    if (blk < 16) {
      float* bs = sh;         // 512
      float* ms = sh + 512;   // 128
      for (int i = tid; i < 512; i += 256) bs[i] = base[blk * 512 + i];
      __syncthreads();
      if (tid < 128) {
        float a0 = 0.f, a1 = 0.f, a2 = 0.f, a3 = 0.f;
        for (int k = 0; k < 512; k += 4) {
          a0 = fmaf(bs[k + 0], mW1[(k + 0) * 128 + tid], a0);
          a1 = fmaf(bs[k + 1], mW1[(k + 1) * 128 + tid], a1);
          a2 = fmaf(bs[k + 2], mW1[(k + 2) * 128 + tid], a2);
          a3 = fmaf(bs[k + 3], mW1[(k + 3) * 128 + tid], a3);
        }
        ms[tid] = fmaxf(mb1[tid] + (a0 + a1) + (a2 + a3), 0.f);
      }
      __syncthreads();
      if (tid < 32) {
        float acc = mb2[tid];
        for (int k = 0; k < 128; ++k) acc = fmaf(ms[k], mW2[k * 32 + tid], acc);
        coefs[blk * 32 + tid] = acc;
      }
    }
  } else {
    // ---- BIG: G3 = xp @ dW1 (unscaled) -> P3 (256 chunks KC=294, 2 passes) ----
    int c = blk - 256;
    int t = c >> 5, il = (c & 31) * 294;
    gemm_body<294, 14, 2>(sh, xp, 9408, il, nullptr, 0,
                          dW1 + ((size_t)t * 9408 + il) * 1024, 1024, P3, c);
  }
  gbar(bar, 5, NB);   // JOIN

  // ---- R3 (per-slice cW1 scale) -> h  (512 blocks, 32 cols x 8 slices, CPS=32) ----
  reduce_phase<32, 16384, 3, 8>(sh, P3, z1, coefs, db1, h, nullptr, blk);
  gbar(bar, 6, NB);

  // ---- G4 = h @ {dW2 scaled, W2} -> P4 (288 chunks KC=32) ----
  if (blk < 288) {
    const float* Bb; const float* sc; int il;
    if (blk < 256) {
      int t = blk >> 5; il = (blk & 31) * 32;
      Bb = dW2 + ((size_t)t * 1024 + il) * 512;
      sc = coefs + t * 4 + 2;                 // cW2[b,t], stride 32
    } else {
      il = (blk - 256) * 32;
      Bb = W2 + (size_t)il * 512;
      sc = nullptr;
    }
    gemm_body<32, 8, 1>(sh, h, 1024, il, sc, 32, Bb, 512, P4, blk);
  }
  gbar(bar, 7, NB);

  // ---- R4 -> out  (256 blocks, 32 cols x 8 slices, CPS=36) ----
  reduce_phase<36, 8192, 4, 8>(sh, P4, b2, coefs, db2, out, nullptr, blk);
}

extern "C" void kernel_launch(void* const* d_in, const int* in_sizes, int n_in,
                              void* d_out, int out_size, void* d_ws, size_t ws_size,
                              hipStream_t stream) {
  const float* x   = (const float*)d_in[0];
  const float* W1  = (const float*)d_in[1];
  const float* b1  = (const float*)d_in[2];
  const float* W2  = (const float*)d_in[3];
  const float* b2  = (const float*)d_in[4];
  const float* dW1 = (const float*)d_in[5];
  const float* db1 = (const float*)d_in[6];
  const float* dW2 = (const float*)d_in[7];
  const float* db2 = (const float*)d_in[8];
  const float* mW1 = (const float*)d_in[9];
  const float* mb1 = (const float*)d_in[10];
  const float* mW2 = (const float*)d_in[11];
  const float* mb2 = (const float*)d_in[12];
  float* out = (float*)d_out;
  float* ws  = (float*)d_ws;
  int*   bar = (int*)d_ws;

  init_kernel<<<32, 256, 0, stream>>>(bar);
  mega_kernel<<<NB, 256, 0, stream>>>(x, W1, b1, W2, b2, dW1, db1, dW2, db2,
                                      mW1, mb1, mW2, mb2, out, ws, bar);
}

// Round 7
// 159.050 us; speedup vs baseline: 4.7889x; 4.7889x over previous
//
#include <hip/hip_runtime.h>
#include <cstdint>
#include <cstddef>

// Sizes: B=16, T=8, K=4, DIN=9408, H1=1024, F=512, MH=128

typedef float f2_t __attribute__((ext_vector_type(2)));
typedef float f4_t __attribute__((ext_vector_type(4)));

// ---------------- 4x4 average pool: x(16,3,224,224) -> xp(16,9408) ----------------
__global__ void pool_kernel(const float* __restrict__ x, float* __restrict__ xp) {
  int idx = blockIdx.x * 256 + threadIdx.x;      // 150528 total
  int bc = idx / 3136;
  int r  = idx - bc * 3136;
  int i  = r / 56;
  int j  = r - i * 56;
  const float* src = x + ((size_t)bc * 224 + 4 * i) * 224 + 4 * j;
  float s = 0.f;
#pragma unroll
  for (int rr = 0; rr < 4; ++rr) {
    float4 v = *reinterpret_cast<const float4*>(src + rr * 224);
    s += v.x + v.y + v.z + v.w;
  }
  xp[idx] = s * 0.0625f;
}

// ---------------- split-K skinny GEMM (M=16), software-pipelined ----------------
// C[b,j] = sum_k A'[b,k]*B[k,j]; A' optionally scaled by coefs4[b*32+t*4] (seg1 only).
// Partials: P[chunk][16][N]. blockIdx.x = chunk c, .y = j-group.
// chunksPerT>0: iLoc0 wraps per t (A re-read per t). Chunks >= chunkSplit: (A2,ldA2,B2), unscaled.
template<int KC, int VEC, int UF, int NT>
__global__ __launch_bounds__(256) void skinny_gemm(
    const float* __restrict__ A, int ldA,
    const float* __restrict__ B,
    const float* __restrict__ A2, int ldA2,
    const float* __restrict__ B2,
    int chunkSplit, int chunksPerT,
    const float* __restrict__ coefs4,
    int N, float* __restrict__ P)
{
  static_assert(KC % UF == 0, "");
  constexpr int NG = KC / UF;
  static_assert(NG >= 2, "");
  __shared__ float a_s[KC * 20];   // [kk][b], stride 20; comp reads broadcast
  const int c = blockIdx.x, tid = threadIdx.x;

  const float* Ab;
  const float* Bb;
  int lda, iLoc0, t = 0;
  bool scaled = false;
  if (c < chunkSplit) {
    Ab = A; lda = ldA;
    if (chunksPerT > 0) {
      t = c / chunksPerT;
      iLoc0 = (c - t * chunksPerT) * KC;
    } else {
      iLoc0 = c * KC;
    }
    scaled = (coefs4 != nullptr);
    Bb = B + (size_t)c * KC * N;
  } else {
    Ab = A2; lda = ldA2;
    iLoc0 = (c - chunkSplit) * KC;
    Bb = B2 + (size_t)iLoc0 * N;
  }

  for (int b = 0; b < 16; ++b) {
    float s = scaled ? coefs4[b * 32 + t * 4] : 1.f;
    const float* Arow = Ab + (size_t)b * lda + iLoc0;
    for (int kk = tid; kk < KC; kk += 256)
      a_s[kk * 20 + b] = s * Arow[kk];
  }
  __syncthreads();

  const int j0 = (blockIdx.y * 256 + tid) * VEC;
  const float* Brow = Bb + j0;

  float acc[16][VEC];
#pragma unroll
  for (int b = 0; b < 16; ++b)
#pragma unroll
    for (int v = 0; v < VEC; ++v) acc[b][v] = 0.f;

  float w0[UF][VEC], w1[UF][VEC];

  auto loadg = [&](float (&W)[UF][VEC], int kb) {
#pragma unroll
    for (int u = 0; u < UF; ++u) {
      const float* p = Brow + (size_t)(kb + u) * N;
      if constexpr (VEC == 2) {
        f2_t v;
        if constexpr (NT) v = __builtin_nontemporal_load(reinterpret_cast<const f2_t*>(p));
        else              v = *reinterpret_cast<const f2_t*>(p);
        W[u][0] = v.x; W[u][1] = v.y;
      } else {
        f4_t v;
        if constexpr (NT) v = __builtin_nontemporal_load(reinterpret_cast<const f4_t*>(p));
        else              v = *reinterpret_cast<const f4_t*>(p);
        W[u][0] = v.x; W[u][1] = v.y; W[u][2] = v.z; W[u][3] = v.w;
      }
    }
  };
  auto comp = [&](const float (&W)[UF][VEC], int kb) {
#pragma unroll
    for (int u = 0; u < UF; ++u) {
      int kk = kb + u;
      const float4 a0 = *reinterpret_cast<const float4*>(&a_s[kk * 20 + 0]);
      const float4 a1 = *reinterpret_cast<const float4*>(&a_s[kk * 20 + 4]);
      const float4 a2 = *reinterpret_cast<const float4*>(&a_s[kk * 20 + 8]);
      const float4 a3 = *reinterpret_cast<const float4*>(&a_s[kk * 20 + 12]);
      const float av[16] = {a0.x, a0.y, a0.z, a0.w, a1.x, a1.y, a1.z, a1.w,
                            a2.x, a2.y, a2.z, a2.w, a3.x, a3.y, a3.z, a3.w};
#pragma unroll
      for (int b = 0; b < 16; ++b)
#pragma unroll
        for (int v = 0; v < VEC; ++v)
          acc[b][v] = fmaf(av[b], W[u][v], acc[b][v]);
    }
  };

  loadg(w0, 0);
  if constexpr (NG % 2 == 0) {
#pragma unroll 1
    for (int g = 0; g + 2 < NG; g += 2) {
      loadg(w1, (g + 1) * UF);
      comp(w0, g * UF);
      loadg(w0, (g + 2) * UF);
      comp(w1, (g + 1) * UF);
    }
    loadg(w1, (NG - 1) * UF);
    comp(w0, (NG - 2) * UF);
    comp(w1, (NG - 1) * UF);
  } else {
#pragma unroll 1
    for (int g = 0; g + 3 < NG; g += 2) {
      loadg(w1, (g + 1) * UF);
      comp(w0, g * UF);
      loadg(w0, (g + 2) * UF);
      comp(w1, (g + 1) * UF);
    }
    loadg(w1, (NG - 2) * UF);
    comp(w0, (NG - 3) * UF);
    loadg(w0, (NG - 1) * UF);
    comp(w1, (NG - 2) * UF);
    comp(w0, (NG - 1) * UF);
  }

  float* Pb = P + (size_t)c * 16 * N + j0;
#pragma unroll
  for (int b = 0; b < 16; ++b) {
    if constexpr (VEC == 2) {
      *reinterpret_cast<float2*>(Pb) = make_float2(acc[b][0], acc[b][1]);
    } else {
      *reinterpret_cast<float4*>(Pb) = make_float4(acc[b][0], acc[b][1], acc[b][2], acc[b][3]);
    }
    Pb += N;
  }
}

// ---------------- fused reduce + epilogue (float4, 16 slices x 16 col-threads) --------
// Block covers 64 f-cols. Thread (fl,s): sums CPS=NCH/16 chunks of float4.
// MODE 1: z1,t1=(+b1,relu)  2: base=(+b2)  3: h=relu(z1+cW1-scaled-sum+db1 term)  4: out
template<int NCH, int MODE, int FTOT>
__global__ __launch_bounds__(256) void reduce4(
    const float* __restrict__ P,
    const float* __restrict__ bias,      // b1(M1), b2(M2,M4), z1(M3)
    const float* __restrict__ coefs,
    const float* __restrict__ dvec,      // db1(M3), db2(M4)
    float* __restrict__ o1, float* __restrict__ o2)
{
  constexpr int CPS = NCH / 16;
  static_assert(NCH % 16 == 0, "");
  __shared__ float4 r[16][17];
  const int fl = threadIdx.x & 15, s = threadIdx.x >> 4;
  const int f = blockIdx.x * 64 + fl * 4;

  const float4* p = reinterpret_cast<const float4*>(P + (size_t)s * CPS * FTOT + f);
  float sx = 0.f, sy = 0.f, sz = 0.f, sw = 0.f;
#pragma unroll 8
  for (int cc = 0; cc < CPS; ++cc) {
    float4 v = *p;
    sx += v.x; sy += v.y; sz += v.z; sw += v.w;
    p += FTOT / 4;
  }
  if constexpr (MODE == 3) {
    int b = f >> 10;
    float sc = coefs[b * 32 + (s >> 1) * 4];   // cW1[b, t = s/2]  (32 chunks/slice, 64/t)
    sx *= sc; sy *= sc; sz *= sc; sw *= sc;
  }
  r[s][fl] = make_float4(sx, sy, sz, sw);
  __syncthreads();

  if (s == 0) {
    float vx = 0.f, vy = 0.f, vz = 0.f, vw = 0.f;
#pragma unroll
    for (int i = 0; i < 16; ++i) {
      float4 t = r[i][fl];
      vx += t.x; vy += t.y; vz += t.z; vw += t.w;
    }
    if constexpr (MODE == 1) {
      float4 bb = *reinterpret_cast<const float4*>(bias + (f & 1023));
      float4 z = make_float4(vx + bb.x, vy + bb.y, vz + bb.z, vw + bb.w);
      *reinterpret_cast<float4*>(o1 + f) = z;
      *reinterpret_cast<float4*>(o2 + f) =
          make_float4(fmaxf(z.x, 0.f), fmaxf(z.y, 0.f), fmaxf(z.z, 0.f), fmaxf(z.w, 0.f));
    } else if constexpr (MODE == 2) {
      float4 bb = *reinterpret_cast<const float4*>(bias + (f & 511));
      *reinterpret_cast<float4*>(o1 + f) =
          make_float4(vx + bb.x, vy + bb.y, vz + bb.z, vw + bb.w);
    } else if constexpr (MODE == 3) {
      int b = f >> 10, j = f & 1023;
      float4 zz = *reinterpret_cast<const float4*>(bias + f);   // z1
      float zx = vx + zz.x, zy = vy + zz.y, zzc = vz + zz.z, zw = vw + zz.w;
#pragma unroll
      for (int t = 0; t < 8; ++t) {
        float c1 = coefs[b * 32 + t * 4 + 1];
        float4 d = *reinterpret_cast<const float4*>(dvec + t * 1024 + j);
        zx = fmaf(c1, d.x, zx); zy = fmaf(c1, d.y, zy);
        zzc = fmaf(c1, d.z, zzc); zw = fmaf(c1, d.w, zw);
      }
      *reinterpret_cast<float4*>(o1 + f) =
          make_float4(fmaxf(zx, 0.f), fmaxf(zy, 0.f), fmaxf(zzc, 0.f), fmaxf(zw, 0.f));
    } else {
      int b = f >> 9, k = f & 511;
      float4 bb = *reinterpret_cast<const float4*>(bias + k);   // b2
      float zx = vx + bb.x, zy = vy + bb.y, zzc = vz + bb.z, zw = vw + bb.w;
#pragma unroll
      for (int t = 0; t < 8; ++t) {
        float c3 = coefs[b * 32 + t * 4 + 3];
        float4 d = *reinterpret_cast<const float4*>(dvec + t * 512 + k);
        zx = fmaf(c3, d.x, zx); zy = fmaf(c3, d.y, zy);
        zzc = fmaf(c3, d.z, zzc); zw = fmaf(c3, d.w, zw);
      }
      *reinterpret_cast<float4*>(o1 + f) = make_float4(zx, zy, zzc, zw);
    }
  }
}

// coefs = (relu(base@mW1+mb1))@mW2+mb2, one block of 1024
__global__ __launch_bounds__(1024) void mcoef_kernel(
    const float* __restrict__ base, const float* __restrict__ mW1, const float* __restrict__ mb1,
    const float* __restrict__ mW2, const float* __restrict__ mb2, float* __restrict__ coefs) {
  __shared__ float bs[16 * 512];
  __shared__ float ms[16 * 128];
  int tid = threadIdx.x;
  for (int i = tid; i < 8192; i += 1024) bs[i] = base[i];
  __syncthreads();
#pragma unroll
  for (int p = 0; p < 2; ++p) {
    int o = p * 1024 + tid;
    int b = o >> 7, col = o & 127;
    float acc = mb1[col];
    const float* br = &bs[b * 512];
    for (int k = 0; k < 512; ++k) acc = fmaf(br[k], mW1[k * 128 + col], acc);
    ms[o] = fmaxf(acc, 0.f);
  }
  __syncthreads();
  if (tid < 512) {
    int b = tid >> 5, o = tid & 31;
    float acc = mb2[o];
    const float* mr = &ms[b * 128];
    for (int k = 0; k < 128; ++k) acc = fmaf(mr[k], mW2[k * 32 + o], acc);
    coefs[b * 32 + o] = acc;
  }
}

extern "C" void kernel_launch(void* const* d_in, const int* in_sizes, int n_in,
                              void* d_out, int out_size, void* d_ws, size_t ws_size,
                              hipStream_t stream) {
  const float* x   = (const float*)d_in[0];
  const float* W1  = (const float*)d_in[1];
  const float* b1  = (const float*)d_in[2];
  const float* W2  = (const float*)d_in[3];
  const float* b2  = (const float*)d_in[4];
  const float* dW1 = (const float*)d_in[5];
  const float* db1 = (const float*)d_in[6];
  const float* dW2 = (const float*)d_in[7];
  const float* db2 = (const float*)d_in[8];
  const float* mW1 = (const float*)d_in[9];
  const float* mb1 = (const float*)d_in[10];
  const float* mW2 = (const float*)d_in[11];
  const float* mb2 = (const float*)d_in[12];
  float* out = (float*)d_out;

  float* ws    = (float*)d_ws;
  float* xp    = ws;                 // 150528
  float* z1    = xp + 150528;        // 16384
  float* t1    = z1 + 16384;         // 16384
  float* base  = t1 + 16384;         // 8192
  float* coefs = base + 8192;        // 512
  float* h     = coefs + 512;        // 16384
  float* P1    = h + 16384;          // 224*16*1024 = 3670016
  float* P2    = P1 + 3670016;       // 128*16*512  = 1048576
  float* P3    = P2 + 1048576;       // 512*16*1024 = 8388608
  float* P4    = P3 + 8388608;       // 288*16*512  = 2359296
  // total ~15.8M floats ~ 63 MB

  const int BIG = 1 << 30;

  // xp = pool(x)
  pool_kernel<<<588, 256, 0, stream>>>(x, xp);

  // G1: xp @ W1 -> P1.  224 chunks KC=42, 2 j-groups (VEC=2) = 448 blocks
  skinny_gemm<42, 2, 7, 1><<<dim3(224, 2), 256, 0, stream>>>(
      xp, 9408, W1, nullptr, 0, nullptr, BIG, 0, nullptr, 1024, P1);
  // R1 -> z1, t1
  reduce4<224, 1, 16384><<<256, 256, 0, stream>>>(P1, b1, nullptr, nullptr, z1, t1);

  // G2: t1 @ W2 -> P2.  128 chunks KC=8 (VEC=2)
  skinny_gemm<8, 2, 4, 0><<<dim3(128, 1), 256, 0, stream>>>(
      t1, 1024, W2, nullptr, 0, nullptr, BIG, 0, nullptr, 512, P2);
  // R2 -> base
  reduce4<128, 2, 8192><<<128, 256, 0, stream>>>(P2, b2, nullptr, nullptr, base, nullptr);

  // coefs
  mcoef_kernel<<<1, 1024, 0, stream>>>(base, mW1, mb1, mW2, mb2, coefs);

  // G3: xp @ dW1 -> P3 (unscaled; scale applied in R3).
  // 512 chunks KC=147 (64 per t), VEC=4 covers all 1024 cols. 2 blocks/CU.
  skinny_gemm<147, 4, 7, 1><<<dim3(512, 1), 256, 0, stream>>>(
      xp, 9408, dW1, nullptr, 0, nullptr, BIG, 64, nullptr, 1024, P3);
  // R3 (cW1 scale per slice) -> h
  reduce4<512, 3, 16384><<<256, 256, 0, stream>>>(P3, z1, coefs, db1, h, nullptr);

  // G4: h @ {dW2 scaled, W2} -> P4.  seg1: 256 chunks KC=32 (32/t); seg2: 32 chunks over W2
  skinny_gemm<32, 2, 8, 1><<<dim3(288, 1), 256, 0, stream>>>(
      h, 1024, dW2, h, 1024, W2, 256, 32, coefs + 2, 512, P4);
  // R4 -> out
  reduce4<288, 4, 8192><<<128, 256, 0, stream>>>(P4, b2, coefs, db2, out, nullptr);
}